// Round 2
// baseline (279.168 us; speedup 1.0000x reference)
//
#include <hip/hip_runtime.h>
#include <hip/hip_bf16.h>

#define B_  2
#define S_  2048
#define D_  1024
#define H_  16
#define HD_ 64

typedef __attribute__((ext_vector_type(8))) short short8;
typedef __attribute__((ext_vector_type(4))) float f32x4;

__device__ __forceinline__ unsigned short f2b(float f) {
    __hip_bfloat16 h = __float2bfloat16(f);
    unsigned short u;
    __builtin_memcpy(&u, &h, 2);
    return u;
}

// ---------------------------------------------------------------------------
// Kernel 0: fp32 -> bf16 conversion for x, Wq, Wk, Wv, Wo into workspace.
// dst layout: xb[4M] | wq[1M] | wk[1M] | wv[1M] | wo[1M]
// ---------------------------------------------------------------------------
__global__ __launch_bounds__(256) void convert_kernel(
    const float* __restrict__ x,  const float* __restrict__ Wq,
    const float* __restrict__ Wk, const float* __restrict__ Wv,
    const float* __restrict__ Wo, unsigned short* __restrict__ dst)
{
    const long long i4 = blockIdx.x * 256 + threadIdx.x;   // 0 .. 2M-1
    const long long e  = i4 * 4;
    const long long M1 = 1048576LL;
    const float* src;
    if      (e < 4 * M1) src = x  + e;
    else if (e < 5 * M1) src = Wq + (e - 4 * M1);
    else if (e < 6 * M1) src = Wk + (e - 5 * M1);
    else if (e < 7 * M1) src = Wv + (e - 6 * M1);
    else                 src = Wo + (e - 7 * M1);
    float4 v = *(const float4*)src;
    unsigned long long pk = (unsigned long long)f2b(v.x)
                          | ((unsigned long long)f2b(v.y) << 16)
                          | ((unsigned long long)f2b(v.z) << 32)
                          | ((unsigned long long)f2b(v.w) << 48);
    *(unsigned long long*)&dst[e] = pk;
}

// ---------------------------------------------------------------------------
// Kernel 1: QKV projection.  out[m][n] = sum_d x[m][d] * W[n][d]  (transpose_b)
// Q,K -> [B][H][S][HD] bf16 ; V -> [B][H][HD][S] bf16 (pre-transposed for PV)
// ---------------------------------------------------------------------------
__global__ __launch_bounds__(256) void qkv_proj_kernel(
    const unsigned short* __restrict__ x,
    const unsigned short* __restrict__ Wq,
    const unsigned short* __restrict__ Wk,
    const unsigned short* __restrict__ Wv,
    unsigned short* __restrict__ q_ws,
    unsigned short* __restrict__ k_ws,
    unsigned short* __restrict__ vT_ws)
{
    __shared__ unsigned short a_lds[64][72];   // 72: 144B row stride, 16B aligned
    __shared__ unsigned short b_lds[64][72];

    const int m0 = blockIdx.x * 64;
    const int n0 = blockIdx.y * 64;
    const int which = blockIdx.z;
    const unsigned short* W = (which == 0) ? Wq : (which == 1) ? Wk : Wv;

    const int tid  = threadIdx.x;
    const int wave = tid >> 6;
    const int lane = tid & 63;
    const int l15  = lane & 15;
    const int quad = lane >> 4;
    const int wm = (wave & 1) * 32;
    const int wn = (wave >> 1) * 32;

    f32x4 acc[2][2];
    #pragma unroll
    for (int sm = 0; sm < 2; ++sm)
        #pragma unroll
        for (int sn = 0; sn < 2; ++sn)
            #pragma unroll
            for (int r = 0; r < 4; ++r) acc[sm][sn][r] = 0.f;

    const int row = tid >> 3;   // 0..31
    const int c8  = tid & 7;    // 0..7

    for (int kk = 0; kk < D_; kk += 64) {
        *(uint4*)&a_lds[row][c8 * 8]      = *(const uint4*)&x[(m0 + row) * D_ + kk + c8 * 8];
        *(uint4*)&a_lds[row + 32][c8 * 8] = *(const uint4*)&x[(m0 + row + 32) * D_ + kk + c8 * 8];
        *(uint4*)&b_lds[row][c8 * 8]      = *(const uint4*)&W[(n0 + row) * D_ + kk + c8 * 8];
        *(uint4*)&b_lds[row + 32][c8 * 8] = *(const uint4*)&W[(n0 + row + 32) * D_ + kk + c8 * 8];
        __syncthreads();
        #pragma unroll
        for (int kc = 0; kc < 2; ++kc) {
            short8 af[2], bf[2];
            #pragma unroll
            for (int s = 0; s < 2; ++s) {
                af[s] = *(const short8*)&a_lds[wm + s * 16 + l15][kc * 32 + quad * 8];
                bf[s] = *(const short8*)&b_lds[wn + s * 16 + l15][kc * 32 + quad * 8];
            }
            #pragma unroll
            for (int sm = 0; sm < 2; ++sm)
                #pragma unroll
                for (int sn = 0; sn < 2; ++sn)
                    acc[sm][sn] = __builtin_amdgcn_mfma_f32_16x16x32_bf16(
                        af[sm], bf[sn], acc[sm][sn], 0, 0, 0);
        }
        __syncthreads();
    }

    // epilogue: D[row=quad*4+r][col=l15]
    #pragma unroll
    for (int sm = 0; sm < 2; ++sm) {
        #pragma unroll
        for (int sn = 0; sn < 2; ++sn) {
            const int n  = n0 + wn + sn * 16 + l15;
            const int h  = n >> 6;
            const int hd = n & 63;
            const int mbase = m0 + wm + sm * 16 + quad * 4;
            const int b     = mbase >> 11;
            const int sbase = mbase & 2047;
            if (which == 2) {
                unsigned long long pk = 0;
                #pragma unroll
                for (int r = 0; r < 4; ++r)
                    pk |= (unsigned long long)f2b(acc[sm][sn][r]) << (16 * r);
                *(unsigned long long*)&vT_ws[((b * H_ + h) * HD_ + hd) * S_ + sbase] = pk;
            } else {
                unsigned short* dst = (which == 0) ? q_ws : k_ws;
                #pragma unroll
                for (int r = 0; r < 4; ++r)
                    dst[((b * H_ + h) * S_ + (sbase + r)) * HD_ + hd] = f2b(acc[sm][sn][r]);
            }
        }
    }
}

// ---------------------------------------------------------------------------
// Kernel 2: causal flash attention. 1 block = (b,h, 64 q-rows); 4 waves x 16 q.
// ---------------------------------------------------------------------------
__global__ __launch_bounds__(256) void attn_kernel(
    const unsigned short* __restrict__ q_ws,
    const unsigned short* __restrict__ k_ws,
    const unsigned short* __restrict__ vT_ws,
    unsigned short* __restrict__ ctx_ws)   // [B*S][D], col = h*64+hd
{
    __shared__ unsigned short q_lds[64][72];
    __shared__ unsigned short k_lds[64][72];
    __shared__ unsigned short vT_lds[64][72];
    __shared__ unsigned short p_lds[4][16][72];

    const int qt = blockIdx.x;   // 0..31
    const int bh = blockIdx.y;   // 0..31 = b*H + h
    const int q0 = qt * 64;

    const int tid  = threadIdx.x;
    const int wave = tid >> 6;
    const int lane = tid & 63;
    const int l15  = lane & 15;
    const int quad = lane >> 4;

    const unsigned short* Qh = q_ws + bh * (S_ * HD_);
    const unsigned short* Kh = k_ws + bh * (S_ * HD_);
    const unsigned short* Vt = vT_ws + bh * (HD_ * S_);

    const int row = tid >> 3;   // 0..31
    const int c8  = tid & 7;

    *(uint4*)&q_lds[row][c8 * 8]      = *(const uint4*)&Qh[(q0 + row) * HD_ + c8 * 8];
    *(uint4*)&q_lds[row + 32][c8 * 8] = *(const uint4*)&Qh[(q0 + row + 32) * HD_ + c8 * 8];
    __syncthreads();

    short8 aq[2];
    aq[0] = *(const short8*)&q_lds[wave * 16 + l15][quad * 8];
    aq[1] = *(const short8*)&q_lds[wave * 16 + l15][32 + quad * 8];

    float M[4], l[4];
    f32x4 o[4];
    #pragma unroll
    for (int r = 0; r < 4; ++r) { M[r] = -1e30f; l[r] = 0.f; }
    #pragma unroll
    for (int f = 0; f < 4; ++f)
        #pragma unroll
        for (int r = 0; r < 4; ++r) o[f][r] = 0.f;

    const int qrow_base = q0 + wave * 16 + quad * 4;

    for (int kt = 0; kt <= qt; ++kt) {
        const int k0 = kt * 64;
        __syncthreads();   // protect k_lds/vT_lds reuse from previous iter
        *(uint4*)&k_lds[row][c8 * 8]      = *(const uint4*)&Kh[(k0 + row) * HD_ + c8 * 8];
        *(uint4*)&k_lds[row + 32][c8 * 8] = *(const uint4*)&Kh[(k0 + row + 32) * HD_ + c8 * 8];
        *(uint4*)&vT_lds[row][c8 * 8]     = *(const uint4*)&Vt[row * S_ + k0 + c8 * 8];
        *(uint4*)&vT_lds[row + 32][c8 * 8]= *(const uint4*)&Vt[(row + 32) * S_ + k0 + c8 * 8];
        __syncthreads();

        // S = Q K^T  (16 q-rows x 64 keys per wave)
        f32x4 sc[4];
        #pragma unroll
        for (int f = 0; f < 4; ++f)
            #pragma unroll
            for (int r = 0; r < 4; ++r) sc[f][r] = 0.f;
        #pragma unroll
        for (int f = 0; f < 4; ++f)
            #pragma unroll
            for (int kc = 0; kc < 2; ++kc) {
                short8 bk = *(const short8*)&k_lds[f * 16 + l15][kc * 32 + quad * 8];
                sc[f] = __builtin_amdgcn_mfma_f32_16x16x32_bf16(aq[kc], bk, sc[f], 0, 0, 0);
            }

        // scale + causal mask + online softmax
        float p[4][4], mloc[4];
        #pragma unroll
        for (int r = 0; r < 4; ++r) mloc[r] = -1e30f;
        #pragma unroll
        for (int f = 0; f < 4; ++f) {
            const int kg = k0 + f * 16 + l15;
            #pragma unroll
            for (int r = 0; r < 4; ++r) {
                float sv = sc[f][r] * 0.125f;          // 1/sqrt(64)
                if (kg > qrow_base + r) sv = -1e30f;   // causal mask
                p[f][r] = sv;
                mloc[r] = fmaxf(mloc[r], sv);
            }
        }
        #pragma unroll
        for (int off = 1; off < 16; off <<= 1)
            #pragma unroll
            for (int r = 0; r < 4; ++r)
                mloc[r] = fmaxf(mloc[r], __shfl_xor(mloc[r], off, 64));

        float alpha[4], rs[4];
        #pragma unroll
        for (int r = 0; r < 4; ++r) {
            float Mn = fmaxf(M[r], mloc[r]);
            alpha[r] = __expf(M[r] - Mn);
            M[r] = Mn;
            rs[r] = 0.f;
        }
        #pragma unroll
        for (int f = 0; f < 4; ++f)
            #pragma unroll
            for (int r = 0; r < 4; ++r) {
                float pv = __expf(p[f][r] - M[r]);   // masked: exp(-1e30 - M) = 0
                p[f][r] = pv;
                rs[r] += pv;
            }
        #pragma unroll
        for (int off = 1; off < 16; off <<= 1)
            #pragma unroll
            for (int r = 0; r < 4; ++r)
                rs[r] += __shfl_xor(rs[r], off, 64);
        #pragma unroll
        for (int r = 0; r < 4; ++r) l[r] = l[r] * alpha[r] + rs[r];

        // P: C-layout -> A-layout via per-wave LDS round-trip (m120 transform)
        #pragma unroll
        for (int f = 0; f < 4; ++f)
            #pragma unroll
            for (int r = 0; r < 4; ++r)
                p_lds[wave][quad * 4 + r][f * 16 + l15] = f2b(p[f][r]);

        #pragma unroll
        for (int f = 0; f < 4; ++f)
            #pragma unroll
            for (int r = 0; r < 4; ++r)
                o[f][r] *= alpha[r];

        __syncthreads();   // insurance: DS write->read ordering (uniform trip count)

        short8 ap[2];
        ap[0] = *(const short8*)&p_lds[wave][l15][quad * 8];
        ap[1] = *(const short8*)&p_lds[wave][l15][32 + quad * 8];
        #pragma unroll
        for (int f = 0; f < 4; ++f)
            #pragma unroll
            for (int kc = 0; kc < 2; ++kc) {
                short8 bv = *(const short8*)&vT_lds[f * 16 + l15][kc * 32 + quad * 8];
                o[f] = __builtin_amdgcn_mfma_f32_16x16x32_bf16(ap[kc], bv, o[f], 0, 0, 0);
            }
    }

    // epilogue: normalize and write ctx[b][s][h*64+hd]
    const int b = bh >> 4;
    const int h = bh & 15;
    #pragma unroll
    for (int f = 0; f < 4; ++f) {
        const int col = h * 64 + f * 16 + l15;
        #pragma unroll
        for (int r = 0; r < 4; ++r) {
            const int qg = qrow_base + r;
            ctx_ws[(b * S_ + qg) * D_ + col] = f2b(o[f][r] / l[r]);
        }
    }
}

// ---------------------------------------------------------------------------
// Kernel 3: output projection + bias.  out[m][n] = sum_d ctx[m][d]*Wo[n][d] + bo[n]
// out is float32.
// ---------------------------------------------------------------------------
__global__ __launch_bounds__(256) void out_proj_kernel(
    const unsigned short* __restrict__ ctx,
    const unsigned short* __restrict__ Wo,
    const float* __restrict__ bo,
    float* __restrict__ out)
{
    __shared__ unsigned short a_lds[64][72];
    __shared__ unsigned short b_lds[64][72];

    const int m0 = blockIdx.x * 64;
    const int n0 = blockIdx.y * 64;

    const int tid  = threadIdx.x;
    const int wave = tid >> 6;
    const int lane = tid & 63;
    const int l15  = lane & 15;
    const int quad = lane >> 4;
    const int wm = (wave & 1) * 32;
    const int wn = (wave >> 1) * 32;

    f32x4 acc[2][2];
    #pragma unroll
    for (int sm = 0; sm < 2; ++sm)
        #pragma unroll
        for (int sn = 0; sn < 2; ++sn)
            #pragma unroll
            for (int r = 0; r < 4; ++r) acc[sm][sn][r] = 0.f;

    const int row = tid >> 3;
    const int c8  = tid & 7;

    for (int kk = 0; kk < D_; kk += 64) {
        *(uint4*)&a_lds[row][c8 * 8]      = *(const uint4*)&ctx[(m0 + row) * D_ + kk + c8 * 8];
        *(uint4*)&a_lds[row + 32][c8 * 8] = *(const uint4*)&ctx[(m0 + row + 32) * D_ + kk + c8 * 8];
        *(uint4*)&b_lds[row][c8 * 8]      = *(const uint4*)&Wo[(n0 + row) * D_ + kk + c8 * 8];
        *(uint4*)&b_lds[row + 32][c8 * 8] = *(const uint4*)&Wo[(n0 + row + 32) * D_ + kk + c8 * 8];
        __syncthreads();
        #pragma unroll
        for (int kc = 0; kc < 2; ++kc) {
            short8 af[2], bf[2];
            #pragma unroll
            for (int s = 0; s < 2; ++s) {
                af[s] = *(const short8*)&a_lds[wm + s * 16 + l15][kc * 32 + quad * 8];
                bf[s] = *(const short8*)&b_lds[wn + s * 16 + l15][kc * 32 + quad * 8];
            }
            #pragma unroll
            for (int sm = 0; sm < 2; ++sm)
                #pragma unroll
                for (int sn = 0; sn < 2; ++sn)
                    acc[sm][sn] = __builtin_amdgcn_mfma_f32_16x16x32_bf16(
                        af[sm], bf[sn], acc[sm][sn], 0, 0, 0);
        }
        __syncthreads();
    }

    #pragma unroll
    for (int sm = 0; sm < 2; ++sm) {
        #pragma unroll
        for (int sn = 0; sn < 2; ++sn) {
            const int n = n0 + wn + sn * 16 + l15;
            const float bias = bo[n];
            const int mbase = m0 + wm + sm * 16 + quad * 4;
            #pragma unroll
            for (int r = 0; r < 4; ++r)
                out[(mbase + r) * D_ + n] = acc[sm][sn][r] + bias;
        }
    }
}

// ---------------------------------------------------------------------------
extern "C" void kernel_launch(void* const* d_in, const int* in_sizes, int n_in,
                              void* d_out, int out_size, void* d_ws, size_t ws_size,
                              hipStream_t stream) {
    const float* x  = (const float*)d_in[0];
    const float* Wq = (const float*)d_in[1];
    const float* Wk = (const float*)d_in[2];
    const float* Wv = (const float*)d_in[3];
    const float* Wo = (const float*)d_in[4];
    const float* bo = (const float*)d_in[5];
    float* out = (float*)d_out;

    const size_t M1 = 1048576;           // 1M elements
    const size_t SZ = 4 * M1;            // B*S*D = 4M elements

    unsigned short* xb  = (unsigned short*)d_ws;     // 4M
    unsigned short* wqb = xb  + SZ;                  // 1M
    unsigned short* wkb = wqb + M1;                  // 1M
    unsigned short* wvb = wkb + M1;                  // 1M
    unsigned short* wob = wvb + M1;                  // 1M
    unsigned short* q_ws   = wob + M1;               // 4M
    unsigned short* k_ws   = q_ws + SZ;              // 4M
    unsigned short* vT_ws  = k_ws + SZ;              // 4M
    unsigned short* ctx_ws = vT_ws + SZ;             // 4M  (total 24M u16 = 48MB)

    convert_kernel<<<dim3(8192), 256, 0, stream>>>(x, Wq, Wk, Wv, Wo, xb);
    qkv_proj_kernel<<<dim3(64, 16, 3), 256, 0, stream>>>(xb, wqb, wkb, wvb, q_ws, k_ws, vT_ws);
    attn_kernel<<<dim3(32, 32), 256, 0, stream>>>(q_ws, k_ws, vT_ws, ctx_ws);
    out_proj_kernel<<<dim3(64, 16), 256, 0, stream>>>(ctx_ws, wob, bo, out);
}

// Round 3
// 202.713 us; speedup vs baseline: 1.3772x; 1.3772x over previous
//
#include <hip/hip_runtime.h>
#include <hip/hip_bf16.h>

#define B_  2
#define S_  2048
#define D_  1024
#define H_  16
#define HD_ 64

typedef __attribute__((ext_vector_type(8))) short short8;
typedef __attribute__((ext_vector_type(4))) float f32x4;

__device__ __forceinline__ unsigned short f2b(float f) {
    __hip_bfloat16 h = __float2bfloat16(f);
    unsigned short u;
    __builtin_memcpy(&u, &h, 2);
    return u;
}

// ---------------------------------------------------------------------------
// Kernel 0: fp32 -> bf16 conversion for x, Wq, Wk, Wv, Wo into workspace.
// ---------------------------------------------------------------------------
__global__ __launch_bounds__(256) void convert_kernel(
    const float* __restrict__ x,  const float* __restrict__ Wq,
    const float* __restrict__ Wk, const float* __restrict__ Wv,
    const float* __restrict__ Wo, unsigned short* __restrict__ dst)
{
    const long long i4 = blockIdx.x * 256 + threadIdx.x;   // 0 .. 2M-1
    const long long e  = i4 * 4;
    const long long M1 = 1048576LL;
    const float* src;
    if      (e < 4 * M1) src = x  + e;
    else if (e < 5 * M1) src = Wq + (e - 4 * M1);
    else if (e < 6 * M1) src = Wk + (e - 5 * M1);
    else if (e < 7 * M1) src = Wv + (e - 6 * M1);
    else                 src = Wo + (e - 7 * M1);
    float4 v = *(const float4*)src;
    unsigned long long pk = (unsigned long long)f2b(v.x)
                          | ((unsigned long long)f2b(v.y) << 16)
                          | ((unsigned long long)f2b(v.z) << 32)
                          | ((unsigned long long)f2b(v.w) << 48);
    *(unsigned long long*)&dst[e] = pk;
}

// ---------------------------------------------------------------------------
// Kernel 1: QKV projection, 128x128 tile, BK=64 (m93-style, 4x4 frags/wave).
// out[m][n] = sum_d x[m][d] * W[n][d]  (transpose_b)
// Q (scaled by 1/8), K -> [B][H][S][HD] ; V -> [B][H][HD][S] (pre-transposed)
// ---------------------------------------------------------------------------
__global__ __launch_bounds__(256) void qkv_proj_kernel(
    const unsigned short* __restrict__ x,
    const unsigned short* __restrict__ Wq,
    const unsigned short* __restrict__ Wk,
    const unsigned short* __restrict__ Wv,
    unsigned short* __restrict__ q_ws,
    unsigned short* __restrict__ k_ws,
    unsigned short* __restrict__ vT_ws)
{
    __shared__ unsigned short a_lds[128][72];
    __shared__ unsigned short b_lds[128][72];

    const int m0 = blockIdx.x * 128;
    const int n0 = blockIdx.y * 128;
    const int which = blockIdx.z;
    const unsigned short* W = (which == 0) ? Wq : (which == 1) ? Wk : Wv;

    const int tid  = threadIdx.x;
    const int wave = tid >> 6;
    const int lane = tid & 63;
    const int l15  = lane & 15;
    const int quad = lane >> 4;
    const int wm = (wave & 1) * 64;
    const int wn = (wave >> 1) * 64;

    f32x4 acc[4][4];
    #pragma unroll
    for (int sm = 0; sm < 4; ++sm)
        #pragma unroll
        for (int sn = 0; sn < 4; ++sn)
            #pragma unroll
            for (int r = 0; r < 4; ++r) acc[sm][sn][r] = 0.f;

    const int row = tid >> 3;   // 0..31
    const int c8  = tid & 7;    // 0..7

    for (int kk = 0; kk < D_; kk += 64) {
        #pragma unroll
        for (int rp = 0; rp < 4; ++rp) {
            *(uint4*)&a_lds[row + rp * 32][c8 * 8] =
                *(const uint4*)&x[(m0 + row + rp * 32) * D_ + kk + c8 * 8];
            *(uint4*)&b_lds[row + rp * 32][c8 * 8] =
                *(const uint4*)&W[(n0 + row + rp * 32) * D_ + kk + c8 * 8];
        }
        __syncthreads();
        #pragma unroll
        for (int kc = 0; kc < 2; ++kc) {
            short8 af[4], bf[4];
            #pragma unroll
            for (int s = 0; s < 4; ++s) {
                af[s] = *(const short8*)&a_lds[wm + s * 16 + l15][kc * 32 + quad * 8];
                bf[s] = *(const short8*)&b_lds[wn + s * 16 + l15][kc * 32 + quad * 8];
            }
            #pragma unroll
            for (int sm = 0; sm < 4; ++sm)
                #pragma unroll
                for (int sn = 0; sn < 4; ++sn)
                    acc[sm][sn] = __builtin_amdgcn_mfma_f32_16x16x32_bf16(
                        af[sm], bf[sn], acc[sm][sn], 0, 0, 0);
        }
        __syncthreads();
    }

    // epilogue: D[row=quad*4+r][col=l15]; Q gets the 1/sqrt(HD) fold
    #pragma unroll
    for (int sm = 0; sm < 4; ++sm) {
        #pragma unroll
        for (int sn = 0; sn < 4; ++sn) {
            const int n  = n0 + wn + sn * 16 + l15;
            const int h  = n >> 6;
            const int hd = n & 63;
            const int mbase = m0 + wm + sm * 16 + quad * 4;
            const int b     = mbase >> 11;
            const int sbase = mbase & 2047;
            if (which == 2) {
                unsigned long long pk = 0;
                #pragma unroll
                for (int r = 0; r < 4; ++r)
                    pk |= (unsigned long long)f2b(acc[sm][sn][r]) << (16 * r);
                *(unsigned long long*)&vT_ws[((b * H_ + h) * HD_ + hd) * S_ + sbase] = pk;
            } else if (which == 0) {
                #pragma unroll
                for (int r = 0; r < 4; ++r)
                    q_ws[((b * H_ + h) * S_ + (sbase + r)) * HD_ + hd] =
                        f2b(acc[sm][sn][r] * 0.125f);
            } else {
                #pragma unroll
                for (int r = 0; r < 4; ++r)
                    k_ws[((b * H_ + h) * S_ + (sbase + r)) * HD_ + hd] =
                        f2b(acc[sm][sn][r]);
            }
        }
    }
}

// ---------------------------------------------------------------------------
// Kernel 2: causal flash attention, pair-balanced (33 k-tile iters per block),
// double-buffered K/V LDS (1 barrier/iter), diagonal-only masking.
// Block = (pair, bh); phases handle q-tiles (31-pair) then (pair).
// ---------------------------------------------------------------------------
__global__ __launch_bounds__(256) void attn_kernel(
    const unsigned short* __restrict__ q_ws,
    const unsigned short* __restrict__ k_ws,
    const unsigned short* __restrict__ vT_ws,
    unsigned short* __restrict__ ctx_ws)   // [B*S][D], col = h*64+hd
{
    __shared__ unsigned short k_lds[2][64][72];
    __shared__ unsigned short vT_lds[2][64][72];
    __shared__ unsigned short q_lds[64][72];
    __shared__ unsigned short p_lds[4][16][72];

    const int pair = blockIdx.x;   // 0..15
    const int bh   = blockIdx.y;   // 0..31

    const int tid  = threadIdx.x;
    const int wave = tid >> 6;
    const int lane = tid & 63;
    const int l15  = lane & 15;
    const int quad = lane >> 4;
    const int row  = tid >> 3;     // 0..31
    const int c8   = tid & 7;

    const unsigned short* Qh = q_ws + bh * (S_ * HD_);
    const unsigned short* Kh = k_ws + bh * (S_ * HD_);
    const unsigned short* Vt = vT_ws + bh * (HD_ * S_);
    const int b = bh >> 4;
    const int h = bh & 15;

    #pragma unroll
    for (int ph = 0; ph < 2; ++ph) {
        const int qt = (ph == 0) ? (31 - pair) : pair;
        const int q0 = qt * 64;
        const int qrow_base = q0 + wave * 16 + quad * 4;

        __syncthreads();   // previous phase readers done before restaging
        // stage Q tile + K/V tile 0 into buffer 0
        *(uint4*)&q_lds[row][c8 * 8]      = *(const uint4*)&Qh[(q0 + row) * HD_ + c8 * 8];
        *(uint4*)&q_lds[row + 32][c8 * 8] = *(const uint4*)&Qh[(q0 + row + 32) * HD_ + c8 * 8];
        *(uint4*)&k_lds[0][row][c8 * 8]       = *(const uint4*)&Kh[row * HD_ + c8 * 8];
        *(uint4*)&k_lds[0][row + 32][c8 * 8]  = *(const uint4*)&Kh[(row + 32) * HD_ + c8 * 8];
        *(uint4*)&vT_lds[0][row][c8 * 8]      = *(const uint4*)&Vt[row * S_ + c8 * 8];
        *(uint4*)&vT_lds[0][row + 32][c8 * 8] = *(const uint4*)&Vt[(row + 32) * S_ + c8 * 8];
        __syncthreads();

        short8 aq[2];
        aq[0] = *(const short8*)&q_lds[wave * 16 + l15][quad * 8];
        aq[1] = *(const short8*)&q_lds[wave * 16 + l15][32 + quad * 8];

        float M[4], l_lane[4];
        f32x4 o[4];
        #pragma unroll
        for (int r = 0; r < 4; ++r) { M[r] = -1e30f; l_lane[r] = 0.f; }
        #pragma unroll
        for (int f = 0; f < 4; ++f)
            #pragma unroll
            for (int r = 0; r < 4; ++r) o[f][r] = 0.f;

        for (int kt = 0; kt <= qt; ++kt) {
            const int cur = kt & 1;
            if (kt < qt) {   // prefetch next tile into the other buffer
                const int nk0 = (kt + 1) * 64;
                const int nb  = cur ^ 1;
                *(uint4*)&k_lds[nb][row][c8 * 8]       = *(const uint4*)&Kh[(nk0 + row) * HD_ + c8 * 8];
                *(uint4*)&k_lds[nb][row + 32][c8 * 8]  = *(const uint4*)&Kh[(nk0 + row + 32) * HD_ + c8 * 8];
                *(uint4*)&vT_lds[nb][row][c8 * 8]      = *(const uint4*)&Vt[row * S_ + nk0 + c8 * 8];
                *(uint4*)&vT_lds[nb][row + 32][c8 * 8] = *(const uint4*)&Vt[(row + 32) * S_ + nk0 + c8 * 8];
            }

            // S = Q K^T (Q pre-scaled by 1/8)
            f32x4 sc[4];
            #pragma unroll
            for (int f = 0; f < 4; ++f)
                #pragma unroll
                for (int r = 0; r < 4; ++r) sc[f][r] = 0.f;
            #pragma unroll
            for (int f = 0; f < 4; ++f)
                #pragma unroll
                for (int kc = 0; kc < 2; ++kc) {
                    short8 bk = *(const short8*)&k_lds[cur][f * 16 + l15][kc * 32 + quad * 8];
                    sc[f] = __builtin_amdgcn_mfma_f32_16x16x32_bf16(aq[kc], bk, sc[f], 0, 0, 0);
                }

            float p[4][4], mloc[4];
            if (kt == qt) {   // diagonal tile: apply causal mask
                const int k0 = kt * 64;
                #pragma unroll
                for (int f = 0; f < 4; ++f) {
                    const int kg = k0 + f * 16 + l15;
                    #pragma unroll
                    for (int r = 0; r < 4; ++r)
                        p[f][r] = (kg > qrow_base + r) ? -1e30f : sc[f][r];
                }
            } else {
                #pragma unroll
                for (int f = 0; f < 4; ++f)
                    #pragma unroll
                    for (int r = 0; r < 4; ++r) p[f][r] = sc[f][r];
            }

            #pragma unroll
            for (int r = 0; r < 4; ++r)
                mloc[r] = fmaxf(fmaxf(p[0][r], p[1][r]), fmaxf(p[2][r], p[3][r]));
            #pragma unroll
            for (int off = 1; off < 16; off <<= 1)
                #pragma unroll
                for (int r = 0; r < 4; ++r)
                    mloc[r] = fmaxf(mloc[r], __shfl_xor(mloc[r], off, 64));

            float alpha[4];
            #pragma unroll
            for (int r = 0; r < 4; ++r) {
                float Mn = fmaxf(M[r], mloc[r]);
                alpha[r] = __expf(M[r] - Mn);
                M[r] = Mn;
            }
            #pragma unroll
            for (int f = 0; f < 4; ++f)
                #pragma unroll
                for (int r = 0; r < 4; ++r)
                    p[f][r] = __expf(p[f][r] - M[r]);   // masked -> 0
            #pragma unroll
            for (int r = 0; r < 4; ++r)
                l_lane[r] = l_lane[r] * alpha[r]
                          + ((p[0][r] + p[1][r]) + (p[2][r] + p[3][r]));

            // P: C-layout -> A-layout via per-wave LDS round-trip
            #pragma unroll
            for (int f = 0; f < 4; ++f)
                #pragma unroll
                for (int r = 0; r < 4; ++r)
                    p_lds[wave][quad * 4 + r][f * 16 + l15] = f2b(p[f][r]);

            #pragma unroll
            for (int f = 0; f < 4; ++f)
                #pragma unroll
                for (int r = 0; r < 4; ++r)
                    o[f][r] *= alpha[r];

            short8 ap[2];
            ap[0] = *(const short8*)&p_lds[wave][l15][quad * 8];
            ap[1] = *(const short8*)&p_lds[wave][l15][32 + quad * 8];
            #pragma unroll
            for (int f = 0; f < 4; ++f)
                #pragma unroll
                for (int kc = 0; kc < 2; ++kc) {
                    short8 bv = *(const short8*)&vT_lds[cur][f * 16 + l15][kc * 32 + quad * 8];
                    o[f] = __builtin_amdgcn_mfma_f32_16x16x32_bf16(ap[kc], bv, o[f], 0, 0, 0);
                }

            __syncthreads();   // buf[cur] readers done; buf[cur^1] writes visible
        }

        // final l reduction (once per phase) + ctx write
        float l[4];
        #pragma unroll
        for (int r = 0; r < 4; ++r) l[r] = l_lane[r];
        #pragma unroll
        for (int off = 1; off < 16; off <<= 1)
            #pragma unroll
            for (int r = 0; r < 4; ++r)
                l[r] += __shfl_xor(l[r], off, 64);

        #pragma unroll
        for (int f = 0; f < 4; ++f) {
            const int col = h * 64 + f * 16 + l15;
            #pragma unroll
            for (int r = 0; r < 4; ++r) {
                const int qg = qrow_base + r;
                ctx_ws[(b * S_ + qg) * D_ + col] = f2b(o[f][r] / l[r]);
            }
        }
    }
}

// ---------------------------------------------------------------------------
// Kernel 3: output projection + bias, 128x128 tile. out is float32.
// ---------------------------------------------------------------------------
__global__ __launch_bounds__(256) void out_proj_kernel(
    const unsigned short* __restrict__ ctx,
    const unsigned short* __restrict__ Wo,
    const float* __restrict__ bo,
    float* __restrict__ out)
{
    __shared__ unsigned short a_lds[128][72];
    __shared__ unsigned short b_lds[128][72];

    const int m0 = blockIdx.x * 128;
    const int n0 = blockIdx.y * 128;

    const int tid  = threadIdx.x;
    const int wave = tid >> 6;
    const int lane = tid & 63;
    const int l15  = lane & 15;
    const int quad = lane >> 4;
    const int wm = (wave & 1) * 64;
    const int wn = (wave >> 1) * 64;

    f32x4 acc[4][4];
    #pragma unroll
    for (int sm = 0; sm < 4; ++sm)
        #pragma unroll
        for (int sn = 0; sn < 4; ++sn)
            #pragma unroll
            for (int r = 0; r < 4; ++r) acc[sm][sn][r] = 0.f;

    const int row = tid >> 3;
    const int c8  = tid & 7;

    for (int kk = 0; kk < D_; kk += 64) {
        #pragma unroll
        for (int rp = 0; rp < 4; ++rp) {
            *(uint4*)&a_lds[row + rp * 32][c8 * 8] =
                *(const uint4*)&ctx[(m0 + row + rp * 32) * D_ + kk + c8 * 8];
            *(uint4*)&b_lds[row + rp * 32][c8 * 8] =
                *(const uint4*)&Wo[(n0 + row + rp * 32) * D_ + kk + c8 * 8];
        }
        __syncthreads();
        #pragma unroll
        for (int kc = 0; kc < 2; ++kc) {
            short8 af[4], bf[4];
            #pragma unroll
            for (int s = 0; s < 4; ++s) {
                af[s] = *(const short8*)&a_lds[wm + s * 16 + l15][kc * 32 + quad * 8];
                bf[s] = *(const short8*)&b_lds[wn + s * 16 + l15][kc * 32 + quad * 8];
            }
            #pragma unroll
            for (int sm = 0; sm < 4; ++sm)
                #pragma unroll
                for (int sn = 0; sn < 4; ++sn)
                    acc[sm][sn] = __builtin_amdgcn_mfma_f32_16x16x32_bf16(
                        af[sm], bf[sn], acc[sm][sn], 0, 0, 0);
        }
        __syncthreads();
    }

    #pragma unroll
    for (int sm = 0; sm < 4; ++sm) {
        #pragma unroll
        for (int sn = 0; sn < 4; ++sn) {
            const int n = n0 + wn + sn * 16 + l15;
            const float bias = bo[n];
            const int mbase = m0 + wm + sm * 16 + quad * 4;
            #pragma unroll
            for (int r = 0; r < 4; ++r)
                out[(mbase + r) * D_ + n] = acc[sm][sn][r] + bias;
        }
    }
}

// ---------------------------------------------------------------------------
extern "C" void kernel_launch(void* const* d_in, const int* in_sizes, int n_in,
                              void* d_out, int out_size, void* d_ws, size_t ws_size,
                              hipStream_t stream) {
    const float* x  = (const float*)d_in[0];
    const float* Wq = (const float*)d_in[1];
    const float* Wk = (const float*)d_in[2];
    const float* Wv = (const float*)d_in[3];
    const float* Wo = (const float*)d_in[4];
    const float* bo = (const float*)d_in[5];
    float* out = (float*)d_out;

    const size_t M1 = 1048576;           // 1M elements
    const size_t SZ = 4 * M1;            // B*S*D = 4M elements

    unsigned short* xb  = (unsigned short*)d_ws;     // 4M
    unsigned short* wqb = xb  + SZ;                  // 1M
    unsigned short* wkb = wqb + M1;                  // 1M
    unsigned short* wvb = wkb + M1;                  // 1M
    unsigned short* wob = wvb + M1;                  // 1M
    unsigned short* q_ws   = wob + M1;               // 4M
    unsigned short* k_ws   = q_ws + SZ;              // 4M
    unsigned short* vT_ws  = k_ws + SZ;              // 4M
    unsigned short* ctx_ws = vT_ws + SZ;             // 4M  (total 24M u16 = 48MB)

    convert_kernel<<<dim3(8192), 256, 0, stream>>>(x, Wq, Wk, Wv, Wo, xb);
    qkv_proj_kernel<<<dim3(32, 8, 3), 256, 0, stream>>>(xb, wqb, wkb, wvb, q_ws, k_ws, vT_ws);
    attn_kernel<<<dim3(16, 32), 256, 0, stream>>>(q_ws, k_ws, vT_ws, ctx_ws);
    out_proj_kernel<<<dim3(32, 8), 256, 0, stream>>>(ctx_ws, wob, bo, out);
}